// Round 10
// baseline (401.637 us; speedup 1.0000x reference)
//
#include <hip/hip_runtime.h>
#include <hip/hip_bf16.h>

typedef __attribute__((ext_vector_type(8))) short short8;
typedef __attribute__((ext_vector_type(4))) float f32x4;

#define EPSV 1e-5f

__device__ __forceinline__ float bf2f(ushort u){
  union { uint i; float f; } x; x.i = ((uint)u) << 16; return x.f;
}
__device__ __forceinline__ ushort f2bf(float f){
  union { float f; uint i; } x; x.f = f;
  uint r = (x.i + 0x7FFFu + ((x.i >> 16) & 1u)) >> 16;
  return (ushort)r;
}

// async global->LDS, 16B/lane: LDS dest = wave-uniform base + lane*16 (linear);
// global source is PER-LANE (enables gather + source-side swizzle). [R4-verified]
__device__ __forceinline__ void gl_lds16(const void* g, void* l){
  __builtin_amdgcn_global_load_lds(
      (const __attribute__((address_space(1))) unsigned int*)g,
      (__attribute__((address_space(3))) unsigned int*)l, 16, 0, 0);
}

// ---------------- init: zero stats, max accumulators, row 0 of x1 ----------------
__global__ void init_kernel(ushort* x1, float* stats, int* maxbuf){
  int i = blockIdx.x * 256 + threadIdx.x;   // 32768 threads
  if (i < 384)  stats[i] = 0.f;
  if (i < 8192) maxbuf[i] = 0;
  if (i < 32768){ int b = i >> 9, c = i & 511; x1[(size_t)b*1025*512 + c] = 0; }
}

// ---------------- zero node-0 rows of x2 (AFTER aug is dead: aug aliases x2) ----------------
__global__ void zero2_kernel(ushort* x2){
  int i = blockIdx.x * 256 + threadIdx.x;   // 16384 threads
  int b = i >> 8, c = i & 255;
  x2[(size_t)b*1025*256 + c] = 0;
}

// ---------------- q_conv: 4 stacked linears, no activations ----------------
__global__ void qconv_kernel(const float* __restrict__ qv,
    const float* __restrict__ W1, const float* __restrict__ b1,
    const float* __restrict__ W2, const float* __restrict__ b2,
    const float* __restrict__ W3, const float* __restrict__ b3,
    const float* __restrict__ W4, const float* __restrict__ b4,
    float* __restrict__ qout){
  __shared__ float v0[96], h1[64], h2[128], h3[64];
  int b = blockIdx.x, t = threadIdx.x;
  if (t < 95) v0[t] = qv[b*95 + t];
  __syncthreads();
  if (t < 64){ float s = b1[t]; for (int i=0;i<95;i++)  s += v0[i]*W1[i*64 + t];  h1[t]=s; }
  __syncthreads();
  if (t < 128){ float s = b2[t]; for (int i=0;i<64;i++)  s += h1[i]*W2[i*128 + t]; h2[t]=s; }
  __syncthreads();
  if (t < 64){ float s = b3[t]; for (int i=0;i<128;i++) s += h2[i]*W3[i*64 + t];  h3[t]=s; }
  __syncthreads();
  if (t < 32){ float s = b4[t]; for (int i=0;i<64;i++)  s += h3[i]*W4[i*32 + t];  qout[b*32 + t]=s; }
}

// ---------------- build augmented input (B,1025,128) bf16 ----------------
__global__ void aug_kernel(const float* __restrict__ trees, const float* __restrict__ q,
                           ushort* __restrict__ aug){
  int n = blockIdx.x;            // 0..1024
  int b = blockIdx.y;            // 0..63
  int c = threadIdx.x;           // 0..127
  float v = (c < 96) ? trees[((size_t)b*1025 + n)*96 + c] : q[b*32 + (c - 96)];
  aug[(((size_t)b*1025 + n) << 7) + c] = f2bf(v);
}

// ---------------- weight transpose: Wt[o][kp*C+c] = Wc[o][c][kp], bf16 ----------------
__global__ void prepw_kernel(const float* __restrict__ wc, ushort* __restrict__ wt,
                             int O, int C){
  int i = blockIdx.x * 256 + threadIdx.x;
  int total = O * 3 * C;
  if (i >= total) return;
  int o  = i / (3*C);
  int K  = i - o*3*C;
  int kp = K / C;
  int c  = K - kp*C;
  wt[i] = f2bf(wc[(o*C + c)*3 + kp]);
}

// ---------------- gathered conv as MFMA GEMM ----------------
// TM x 128 tile, BK=32, m97 structure: BOTH operands staged via
// global_load_lds (A = per-lane gathered source, B = streamed), simple
// 2-buffer + __syncthreads loop. Source-side XOR swizzle (R4-verified):
// lane l fetches logical 16B-chunk (l&3)^((l>>3)&3) of its row -> LDS phys
// chunk l&3; frag reads apply fc = (fg^((fr>>1)&3))*8 -> 0 bank conflicts.
template<int CIN, int GY, int TM, bool DO_MAX>
__global__ __launch_bounds__(256) void conv_kernel(
    const ushort* __restrict__ xin, const ushort* __restrict__ wt,
    const float* __restrict__ bias, const int* __restrict__ idxes,
    ushort* __restrict__ xout, float* __restrict__ stats, int* __restrict__ maxbuf){
  constexpr int K3    = 3 * CIN;
  constexpr int NT    = K3 / 32;
  constexpr int LOG2C = (CIN == 128) ? 7 : (CIN == 256) ? 8 : 9;
  constexpr int MT    = 1024 / TM;        // m-tiles
  constexpr int MF    = TM / 32;          // m-frags per wave
  constexpr int COUT  = GY * 128;
  constexpr int NWG   = MT * GY * 64;

  // XCD swizzle (verified FETCH drop): contiguous wu range per XCD.
  const int bid  = blockIdx.x;
  const int wu   = (bid & 7) * (NWG >> 3) + (bid >> 3);
  const int m0   = (wu % MT) * TM;
  const int rest = wu / MT;
  const int o0   = (rest % GY) * 128;
  const int b    = rest / GY;

  const int t = threadIdx.x;
  const int lane = t & 63, wid = t >> 6;
  const int WM = (wid & 1) * (TM/2), WO = (wid >> 1) * 64;
  const int fr = lane & 15, fg = lane >> 4;
  const int fc = (fg ^ ((fr >> 1) & 3)) * 8;   // swizzled read column (ushorts)

  __shared__ __align__(16) ushort As[2][TM][32];    // TM=128: 16KB, TM=64: 8KB
  __shared__ __align__(16) ushort Bs[2][128][32];   // 16KB
  __shared__ int idx_s[3*TM];

  for (int i = t; i < 3*TM; i += 256) idx_s[i] = idxes[b*3072 + m0*3 + i];
  __syncthreads();

  // per-lane staging geometry: instr j of wave covers 16 rows starting at
  // (j*4+wid)*16; lane l -> row base+(l>>2), fetches logical chunk
  // (l&3)^((l>>3)&3)  (source swizzle; (row>>1)&3 == (l>>3)&3 within group).
  const int coff = ((lane & 3) ^ ((lane >> 3) & 3)) * 8;   // ushort offset
  const int rA0  = wid*16 + (lane >> 2);
  const int rA1  = (4 + wid)*16 + (lane >> 2);             // TM==128 only
  const uint oA00 = (uint)idx_s[rA0*3 + 0]*CIN + coff;
  const uint oA01 = (uint)idx_s[rA0*3 + 1]*CIN + coff;
  const uint oA02 = (uint)idx_s[rA0*3 + 2]*CIN + coff;
  uint oA10 = 0, oA11 = 0, oA12 = 0;
  if (TM == 128){
    oA10 = (uint)idx_s[rA1*3 + 0]*CIN + coff;
    oA11 = (uint)idx_s[rA1*3 + 1]*CIN + coff;
    oA12 = (uint)idx_s[rA1*3 + 2]*CIN + coff;
  }
  const uint oB0 = (uint)(o0 + wid*16     + (lane >> 2)) * K3 + coff;
  const uint oB1 = (uint)(o0 + (4+wid)*16 + (lane >> 2)) * K3 + coff;
  const ushort* xb = xin + (size_t)b * 1025 * CIN;

  auto STAGE = [&](int ch, int bf){
    const int k0 = ch * 32;
    const int kp = k0 >> LOG2C;
    const int c0 = k0 & (CIN - 1);
    const uint oa0 = (kp == 0) ? oA00 : (kp == 1) ? oA01 : oA02;
    gl_lds16(xb + oa0 + c0, &As[bf][wid*16][0]);
    if (TM == 128){
      const uint oa1 = (kp == 0) ? oA10 : (kp == 1) ? oA11 : oA12;
      gl_lds16(xb + oa1 + c0, &As[bf][(TM==128 ? (4+wid)*16 : 0)][0]);
    }
    gl_lds16(wt + oB0 + k0, &Bs[bf][wid*16][0]);
    gl_lds16(wt + oB1 + k0, &Bs[bf][(4+wid)*16][0]);
  };

  f32x4 acc[MF][4] = {};
  auto COMPUTE = [&](int cur){
    short8 af[MF], bf4[4];
    #pragma unroll
    for (int i = 0; i < MF; ++i)
      af[i] = *reinterpret_cast<const short8*>(&As[cur][WM + i*16 + fr][fc]);
    #pragma unroll
    for (int i = 0; i < 4; ++i)
      bf4[i] = *reinterpret_cast<const short8*>(&Bs[cur][WO + i*16 + fr][fc]);
    __builtin_amdgcn_s_setprio(1);
    #pragma unroll
    for (int mf = 0; mf < MF; ++mf)
      #pragma unroll
      for (int nf = 0; nf < 4; ++nf)
        acc[mf][nf] = __builtin_amdgcn_mfma_f32_16x16x32_bf16(af[mf], bf4[nf], acc[mf][nf], 0, 0, 0);
    __builtin_amdgcn_s_setprio(0);
  };

  STAGE(0, 0);
  __syncthreads();                        // drains DMA (vmcnt 0) -> buf0 ready

  for (int ch = 0; ch < NT; ++ch){
    if (ch + 1 < NT) STAGE(ch + 1, (ch + 1) & 1);   // DMA into other buffer
    COMPUTE(ch & 1);
    __syncthreads();                      // next buf ready + reads of cur done
  }

  // ---- epilogue: bias, stats, optional max, store (no LDS use) ----
  float bsv[4];
  #pragma unroll
  for (int nf = 0; nf < 4; ++nf) bsv[nf] = bias[o0 + WO + nf*16 + fr];
  float lsum = 0.f, lsq = 0.f;
  float cmax[4] = { -1e30f, -1e30f, -1e30f, -1e30f };
  #pragma unroll
  for (int mf = 0; mf < MF; ++mf)
    #pragma unroll
    for (int nf = 0; nf < 4; ++nf)
      #pragma unroll
      for (int i = 0; i < 4; ++i){
        float v = acc[mf][nf][i] + bsv[nf];
        lsum += v; lsq += v*v;
        if (DO_MAX) cmax[nf] = fmaxf(cmax[nf], v);
        else acc[mf][nf][i] = v;
      }
  #pragma unroll
  for (int off = 1; off < 64; off <<= 1){
    lsum += __shfl_xor(lsum, off);
    lsq  += __shfl_xor(lsq,  off);
  }
  if (lane == 0){
    atomicAdd(&stats[b],      lsum);
    atomicAdd(&stats[64 + b], lsq);
  }
  if (DO_MAX){
    #pragma unroll
    for (int nf = 0; nf < 4; ++nf){
      float v = cmax[nf];
      v = fmaxf(v, __shfl_xor(v, 16));
      v = fmaxf(v, __shfl_xor(v, 32));
      if (lane < 16)
        atomicMax(&maxbuf[b*COUT + o0 + WO + nf*16 + fr], __float_as_int(v));
    }
  } else {
    ushort* orow = xout + ((size_t)(b*1025 + 1 + m0 + WM + fg*4))*COUT + o0 + WO + fr;
    #pragma unroll
    for (int mf = 0; mf < MF; ++mf)
      #pragma unroll
      for (int i = 0; i < 4; ++i){
        ushort* pr = orow + (size_t)(mf*16 + i)*COUT;
        #pragma unroll
        for (int nf = 0; nf < 4; ++nf)
          pr[nf*16] = f2bf(acc[mf][nf][i]);
      }
  }
}

// ---------------- in-place TreeLayerNorm + leaky_relu, bf16x8 vectorized ----------------
__global__ void norm_kernel(ushort* __restrict__ x, const float* __restrict__ st,
                            float cnt, int nvec_per_b){
  int b = blockIdx.y;
  int j = blockIdx.x * 256 + threadIdx.x;
  if (j >= nvec_per_b) return;
  float sum = st[b], sq = st[64 + b];
  float mean = sum / cnt;
  float var  = fmaxf((sq - sum*sum/cnt) / (cnt - 1.f), 0.f);
  float rs   = 1.f / (sqrtf(var) + EPSV);
  ushort* p = x + ((size_t)b * nvec_per_b + j) * 8;
  union { uint4 v; ushort u[8]; } d;
  d.v = *reinterpret_cast<const uint4*>(p);
  #pragma unroll
  for (int k = 0; k < 8; ++k){
    float f = bf2f(d.u[k]);
    f = (f - mean) * rs;
    f = (f >= 0.f) ? f : 0.01f * f;
    d.u[k] = f2bf(f);
  }
  *reinterpret_cast<uint4*>(p) = d.v;
}

// ---------------- final: normalize the per-channel max ----------------
__global__ void final_kernel(const int* __restrict__ maxbuf, const float* __restrict__ st,
                             float* __restrict__ out){
  int i = blockIdx.x * 256 + threadIdx.x;   // 8192
  int b = i >> 7;
  const float cnt = 131200.f;
  float sum = st[b], sq = st[64 + b];
  float mean = sum / cnt;
  float var  = fmaxf((sq - sum*sum/cnt) / (cnt - 1.f), 0.f);
  float rs   = 1.f / (sqrtf(var) + EPSV);
  out[i] = (__int_as_float(maxbuf[i]) - mean) * rs;
}

// ---------------- workspace layout ----------------
static constexpr size_t SZ_X1  = (size_t)64*1025*512*2;   // 67,174,400
static constexpr size_t SZ_X2  = (size_t)64*1025*256*2;   // 33,587,200
static constexpr size_t OFF_X1 = 0;
static constexpr size_t OFF_X2 = OFF_X1 + SZ_X1;
static constexpr size_t OFF_AUG = OFF_X2;                 // alias: aug dead after conv1
static constexpr size_t OFF_WT1 = OFF_X2 + SZ_X2;
static constexpr size_t OFF_WT2 = OFF_WT1 + (size_t)512*384*2;
static constexpr size_t OFF_WT3 = OFF_WT2 + (size_t)256*1536*2;
static constexpr size_t OFF_Q   = OFF_WT3 + (size_t)128*768*2;
static constexpr size_t OFF_ST  = OFF_Q + (size_t)64*32*4;
static constexpr size_t OFF_MAX = OFF_ST + (size_t)384*4;

extern "C" void kernel_launch(void* const* d_in, const int* in_sizes, int n_in,
                              void* d_out, int out_size, void* d_ws, size_t ws_size,
                              hipStream_t stream){
  const float* q_vecs = (const float*)d_in[0];
  const float* trees  = (const float*)d_in[1];
  const int*   idxes  = (const int*)  d_in[2];
  const float* Wq1 = (const float*)d_in[3];  const float* bq1 = (const float*)d_in[4];
  const float* Wq2 = (const float*)d_in[5];  const float* bq2 = (const float*)d_in[6];
  const float* Wq3 = (const float*)d_in[7];  const float* bq3 = (const float*)d_in[8];
  const float* Wq4 = (const float*)d_in[9];  const float* bq4 = (const float*)d_in[10];
  const float* Wc1 = (const float*)d_in[11]; const float* bc1 = (const float*)d_in[12];
  const float* Wc2 = (const float*)d_in[13]; const float* bc2 = (const float*)d_in[14];
  const float* Wc3 = (const float*)d_in[15]; const float* bc3 = (const float*)d_in[16];
  float* out = (float*)d_out;
  char* ws = (char*)d_ws;

  ushort* x1    = (ushort*)(ws + OFF_X1);
  ushort* x2    = (ushort*)(ws + OFF_X2);
  ushort* aug   = (ushort*)(ws + OFF_AUG);
  ushort* wt1   = (ushort*)(ws + OFF_WT1);
  ushort* wt2   = (ushort*)(ws + OFF_WT2);
  ushort* wt3   = (ushort*)(ws + OFF_WT3);
  float*  qbuf  = (float*) (ws + OFF_Q);
  float*  stats = (float*) (ws + OFF_ST);
  int*    maxb  = (int*)   (ws + OFF_MAX);

  init_kernel<<<128, 256, 0, stream>>>(x1, stats, maxb);
  qconv_kernel<<<64, 128, 0, stream>>>(q_vecs, Wq1,bq1, Wq2,bq2, Wq3,bq3, Wq4,bq4, qbuf);
  aug_kernel<<<dim3(1025, 64), 128, 0, stream>>>(trees, qbuf, aug);
  prepw_kernel<<<(512*384 + 255)/256, 256, 0, stream>>>(Wc1, wt1, 512, 128);
  prepw_kernel<<<(256*1536 + 255)/256, 256, 0, stream>>>(Wc2, wt2, 256, 512);
  prepw_kernel<<<(128*768 + 255)/256, 256, 0, stream>>>(Wc3, wt3, 128, 256);

  conv_kernel<128, 4, 128, false><<<2048, 256, 0, stream>>>(aug, wt1, bc1, idxes, x1, stats +   0, nullptr);
  zero2_kernel<<<64, 256, 0, stream>>>(x2);   // aug (aliased with x2) is dead now
  norm_kernel<<<dim3((65600 + 255)/256, 64), 256, 0, stream>>>(x1, stats +   0, 524800.f, 65600);
  conv_kernel<512, 2, 128, false><<<1024, 256, 0, stream>>>(x1,  wt2, bc2, idxes, x2, stats + 128, nullptr);
  norm_kernel<<<dim3((32800 + 255)/256, 64), 256, 0, stream>>>(x2, stats + 128, 262400.f, 32800);
  conv_kernel<256, 1, 64, true ><<<1024, 256, 0, stream>>>(x2,  wt3, bc3, idxes, nullptr, stats + 256, maxb);
  final_kernel<<<32, 256, 0, stream>>>(maxb, stats + 256, out);
}

// Round 11
// 271.805 us; speedup vs baseline: 1.4777x; 1.4777x over previous
//
#include <hip/hip_runtime.h>
#include <hip/hip_bf16.h>

typedef __attribute__((ext_vector_type(8))) short short8;
typedef __attribute__((ext_vector_type(4))) float f32x4;

#define EPSV 1e-5f

__device__ __forceinline__ float bf2f(ushort u){
  union { uint i; float f; } x; x.i = ((uint)u) << 16; return x.f;
}
__device__ __forceinline__ ushort f2bf(float f){
  union { float f; uint i; } x; x.f = f;
  uint r = (x.i + 0x7FFFu + ((x.i >> 16) & 1u)) >> 16;
  return (ushort)r;
}

// ---------------- init: zero stats, max accumulators, row 0 of x1 ----------------
__global__ void init_kernel(ushort* x1, float* stats, int* maxbuf){
  int i = blockIdx.x * 256 + threadIdx.x;   // 32768 threads
  if (i < 384)  stats[i] = 0.f;
  if (i < 8192) maxbuf[i] = 0;
  if (i < 32768){ int b = i >> 9, c = i & 511; x1[(size_t)b*1025*512 + c] = 0; }
}

// ---------------- zero node-0 rows of x2 (AFTER aug is dead: aug aliases x2) ----------------
__global__ void zero2_kernel(ushort* x2){
  int i = blockIdx.x * 256 + threadIdx.x;   // 16384 threads
  int b = i >> 8, c = i & 255;
  x2[(size_t)b*1025*256 + c] = 0;
}

// ---------------- q_conv: 4 stacked linears, no activations ----------------
__global__ void qconv_kernel(const float* __restrict__ qv,
    const float* __restrict__ W1, const float* __restrict__ b1,
    const float* __restrict__ W2, const float* __restrict__ b2,
    const float* __restrict__ W3, const float* __restrict__ b3,
    const float* __restrict__ W4, const float* __restrict__ b4,
    float* __restrict__ qout){
  __shared__ float v0[96], h1[64], h2[128], h3[64];
  int b = blockIdx.x, t = threadIdx.x;
  if (t < 95) v0[t] = qv[b*95 + t];
  __syncthreads();
  if (t < 64){ float s = b1[t]; for (int i=0;i<95;i++)  s += v0[i]*W1[i*64 + t];  h1[t]=s; }
  __syncthreads();
  if (t < 128){ float s = b2[t]; for (int i=0;i<64;i++)  s += h1[i]*W2[i*128 + t]; h2[t]=s; }
  __syncthreads();
  if (t < 64){ float s = b3[t]; for (int i=0;i<128;i++) s += h2[i]*W3[i*64 + t];  h3[t]=s; }
  __syncthreads();
  if (t < 32){ float s = b4[t]; for (int i=0;i<64;i++)  s += h3[i]*W4[i*32 + t];  qout[b*32 + t]=s; }
}

// ---------------- build augmented input (B,1025,128) bf16 ----------------
__global__ void aug_kernel(const float* __restrict__ trees, const float* __restrict__ q,
                           ushort* __restrict__ aug){
  int n = blockIdx.x;            // 0..1024
  int b = blockIdx.y;            // 0..63
  int c = threadIdx.x;           // 0..127
  float v = (c < 96) ? trees[((size_t)b*1025 + n)*96 + c] : q[b*32 + (c - 96)];
  aug[(((size_t)b*1025 + n) << 7) + c] = f2bf(v);
}

// ---------------- weight transpose: Wt[o][kp*C+c] = Wc[o][c][kp], bf16 ----------------
__global__ void prepw_kernel(const float* __restrict__ wc, ushort* __restrict__ wt,
                             int O, int C){
  int i = blockIdx.x * 256 + threadIdx.x;
  int total = O * 3 * C;
  if (i >= total) return;
  int o  = i / (3*C);
  int K  = i - o*3*C;
  int kp = K / C;
  int c  = K - kp*C;
  wt[i] = f2bf(wc[(o*C + c)*3 + kp]);
}

// ---------------- gathered conv as MFMA GEMM ----------------
// TM x (GY*?128) tile, BK=32, reg-staged 2-deep prefetch (R7 structure, best
// measured). LDS linear [buf][rows][32]; 16B-chunk XOR swizzle
// phys = log ^ ((row>>1)&3) on write AND read -> 0 conflicts (verified R6).
// TM=128: thread stages 2 A-chunks (row t>>1); TM=64: 1 A-chunk (row t>>2).
template<int CIN, int GY, int TM, bool DO_MAX>
__global__ __launch_bounds__(256) void conv_kernel(
    const ushort* __restrict__ xin, const ushort* __restrict__ wt,
    const float* __restrict__ bias, const int* __restrict__ idxes,
    ushort* __restrict__ xout, float* __restrict__ stats, int* __restrict__ maxbuf){
  constexpr int K3    = 3 * CIN;
  constexpr int NT    = K3 / 32;          // K-chunks of 32 (even)
  constexpr int LOG2  = (CIN == 128) ? 7 : (CIN == 256) ? 8 : 9;
  constexpr int MT    = 1024 / TM;
  constexpr int MF    = TM / 32;          // m-frags per wave
  constexpr int COUT  = GY * 128;
  constexpr int NWG   = MT * GY * 64;

  // XCD swizzle (verified FETCH drop): contiguous wu range per XCD.
  const int bid  = blockIdx.x;
  const int wu   = (bid & 7) * (NWG >> 3) + (bid >> 3);
  const int m0   = (wu % MT) * TM;
  const int rest = wu / MT;
  const int o0   = (rest % GY) * 128;
  const int b    = rest / GY;

  const int t = threadIdx.x;
  const int lane = t & 63, wid = t >> 6;
  const int WM = (wid & 1) * (TM/2), WO = (wid >> 1) * 64;
  const int fr = lane & 15, fg = lane >> 4;
  const int fc = (fg ^ ((fr >> 1) & 3)) * 8;   // swizzled read column (ushorts)

  __shared__ __align__(16) ushort As[2][TM][32];    // TM=128:16KB, TM=64:8KB
  __shared__ __align__(16) ushort Bs[2][128][32];   // 16KB
  __shared__ int idx_s[3*TM];

  for (int i = t; i < 3*TM; i += 256) idx_s[i] = idxes[b*3072 + m0*3 + i];
  __syncthreads();

  // B staging (all TM): thread t -> row rB=t>>1, logical chunks 2h,2h+1 (h=t&1)
  const int rB = t >> 1, h = t & 1, sxB = (rB >> 1) & 3;
  const int pB0 = ((2*h)     ^ sxB) * 8;
  const int pB1 = ((2*h + 1) ^ sxB) * 8;
  const ushort* wrow = wt + (size_t)(o0 + rB) * K3 + h*16;

  // A staging geometry
  const int rA  = (TM == 128) ? (t >> 1) : (t >> 2);
  const int qA  = (TM == 128) ? 0 : (t & 3);            // TM=64: one chunk
  const int sxA = (rA >> 1) & 3;
  const int pA0 = (TM == 128) ? (((2*h) ^ sxA) * 8) : (((qA) ^ sxA) * 8);
  const int pA1 = ((2*h + 1) ^ sxA) * 8;                // TM=128 only
  const int aoff = (TM == 128) ? h*16 : qA*8;
  const int n0 = idx_s[rA*3 + 0], n1 = idx_s[rA*3 + 1], n2 = idx_s[rA*3 + 2];
  const ushort* xb  = xin + (size_t)b * 1025 * CIN;
  const ushort* pA0g = xb + (size_t)n0 * CIN + aoff;
  const ushort* pA1g = xb + (size_t)n1 * CIN + aoff;
  const ushort* pA2g = xb + (size_t)n2 * CIN + aoff;

  // two prefetch register sets — named scalars only (no scratch; R5 lesson)
  uint4 a00, a01, a10, a11, b00, b01, b10, b11;

  auto GLOAD0 = [&](int ch){
    const int k0 = ch * 32;
    const int kp = k0 >> LOG2;
    const int c0 = k0 - (kp << LOG2);
    const ushort* sa = ((kp == 0) ? pA0g : (kp == 1) ? pA1g : pA2g) + c0;
    a00 = *reinterpret_cast<const uint4*>(sa);
    if constexpr (TM == 128) a01 = *reinterpret_cast<const uint4*>(sa + 8);
    const ushort* sb = wrow + k0;
    b00 = *reinterpret_cast<const uint4*>(sb);
    b01 = *reinterpret_cast<const uint4*>(sb + 8);
  };
  auto GLOAD1 = [&](int ch){
    const int k0 = ch * 32;
    const int kp = k0 >> LOG2;
    const int c0 = k0 - (kp << LOG2);
    const ushort* sa = ((kp == 0) ? pA0g : (kp == 1) ? pA1g : pA2g) + c0;
    a10 = *reinterpret_cast<const uint4*>(sa);
    if constexpr (TM == 128) a11 = *reinterpret_cast<const uint4*>(sa + 8);
    const ushort* sb = wrow + k0;
    b10 = *reinterpret_cast<const uint4*>(sb);
    b11 = *reinterpret_cast<const uint4*>(sb + 8);
  };
  auto DSW0 = [&](int bf){
    *reinterpret_cast<uint4*>(&As[bf][rA][pA0]) = a00;
    if constexpr (TM == 128) *reinterpret_cast<uint4*>(&As[bf][rA][pA1]) = a01;
    *reinterpret_cast<uint4*>(&Bs[bf][rB][pB0]) = b00;
    *reinterpret_cast<uint4*>(&Bs[bf][rB][pB1]) = b01;
  };
  auto DSW1 = [&](int bf){
    *reinterpret_cast<uint4*>(&As[bf][rA][pA0]) = a10;
    if constexpr (TM == 128) *reinterpret_cast<uint4*>(&As[bf][rA][pA1]) = a11;
    *reinterpret_cast<uint4*>(&Bs[bf][rB][pB0]) = b10;
    *reinterpret_cast<uint4*>(&Bs[bf][rB][pB1]) = b11;
  };

  f32x4 acc[MF][4] = {};
  auto COMPUTE = [&](int cur){
    short8 af[MF], bf4[4];
    #pragma unroll
    for (int i = 0; i < MF; ++i)
      af[i] = *reinterpret_cast<const short8*>(&As[cur][WM + i*16 + fr][fc]);
    #pragma unroll
    for (int i = 0; i < 4; ++i)
      bf4[i] = *reinterpret_cast<const short8*>(&Bs[cur][WO + i*16 + fr][fc]);
    __builtin_amdgcn_s_setprio(1);
    #pragma unroll
    for (int mf = 0; mf < MF; ++mf)
      #pragma unroll
      for (int nf = 0; nf < 4; ++nf)
        acc[mf][nf] = __builtin_amdgcn_mfma_f32_16x16x32_bf16(af[mf], bf4[nf], acc[mf][nf], 0, 0, 0);
    __builtin_amdgcn_s_setprio(0);
  };

  // prologue: chunk0 -> LDS buf0, chunk1 -> set1
  GLOAD0(0);
  DSW0(0);
  GLOAD1(1);
  __syncthreads();

  for (int ch = 0; ch < NT; ch += 2){
    if (ch + 2 < NT) GLOAD0(ch + 2);     // issue 2 ahead
    COMPUTE(0);
    DSW1(1);                             // waits only set1's loads
    __syncthreads();
    if (ch + 3 < NT) GLOAD1(ch + 3);
    COMPUTE(1);
    if (ch + 2 < NT){
      DSW0(0);
      __syncthreads();
    }
  }

  // ---- epilogue: bias, stats, optional max, direct stores ----
  float bsv[4];
  #pragma unroll
  for (int nf = 0; nf < 4; ++nf) bsv[nf] = bias[o0 + WO + nf*16 + fr];
  float lsum = 0.f, lsq = 0.f;
  float cmax[4] = { -1e30f, -1e30f, -1e30f, -1e30f };
  #pragma unroll
  for (int mf = 0; mf < MF; ++mf)
    #pragma unroll
    for (int nf = 0; nf < 4; ++nf)
      #pragma unroll
      for (int i = 0; i < 4; ++i){
        float v = acc[mf][nf][i] + bsv[nf];
        lsum += v; lsq += v*v;
        if (DO_MAX) cmax[nf] = fmaxf(cmax[nf], v);
        else acc[mf][nf][i] = v;
      }
  #pragma unroll
  for (int off = 1; off < 64; off <<= 1){
    lsum += __shfl_xor(lsum, off);
    lsq  += __shfl_xor(lsq,  off);
  }
  if (lane == 0){
    atomicAdd(&stats[b],      lsum);
    atomicAdd(&stats[64 + b], lsq);
  }
  if (DO_MAX){
    #pragma unroll
    for (int nf = 0; nf < 4; ++nf){
      float v = cmax[nf];
      v = fmaxf(v, __shfl_xor(v, 16));
      v = fmaxf(v, __shfl_xor(v, 32));
      if (lane < 16)
        atomicMax(&maxbuf[b*COUT + o0 + WO + nf*16 + fr], __float_as_int(v));
    }
  } else {
    ushort* orow = xout + ((size_t)(b*1025 + 1 + m0 + WM + fg*4))*COUT + o0 + WO + fr;
    #pragma unroll
    for (int mf = 0; mf < MF; ++mf)
      #pragma unroll
      for (int i = 0; i < 4; ++i){
        ushort* pr = orow + (size_t)(mf*16 + i)*COUT;
        #pragma unroll
        for (int nf = 0; nf < 4; ++nf)
          pr[nf*16] = f2bf(acc[mf][nf][i]);
      }
  }
}

// ---------------- in-place TreeLayerNorm + leaky_relu, bf16x8 vectorized ----------------
__global__ void norm_kernel(ushort* __restrict__ x, const float* __restrict__ st,
                            float cnt, int nvec_per_b){
  int b = blockIdx.y;
  int j = blockIdx.x * 256 + threadIdx.x;
  if (j >= nvec_per_b) return;
  float sum = st[b], sq = st[64 + b];
  float mean = sum / cnt;
  float var  = fmaxf((sq - sum*sum/cnt) / (cnt - 1.f), 0.f);
  float rs   = 1.f / (sqrtf(var) + EPSV);
  ushort* p = x + ((size_t)b * nvec_per_b + j) * 8;
  union { uint4 v; ushort u[8]; } d;
  d.v = *reinterpret_cast<const uint4*>(p);
  #pragma unroll
  for (int k = 0; k < 8; ++k){
    float f = bf2f(d.u[k]);
    f = (f - mean) * rs;
    f = (f >= 0.f) ? f : 0.01f * f;
    d.u[k] = f2bf(f);
  }
  *reinterpret_cast<uint4*>(p) = d.v;
}

// ---------------- final: normalize the per-channel max ----------------
__global__ void final_kernel(const int* __restrict__ maxbuf, const float* __restrict__ st,
                             float* __restrict__ out){
  int i = blockIdx.x * 256 + threadIdx.x;   // 8192
  int b = i >> 7;
  const float cnt = 131200.f;
  float sum = st[b], sq = st[64 + b];
  float mean = sum / cnt;
  float var  = fmaxf((sq - sum*sum/cnt) / (cnt - 1.f), 0.f);
  float rs   = 1.f / (sqrtf(var) + EPSV);
  out[i] = (__int_as_float(maxbuf[i]) - mean) * rs;
}

// ---------------- workspace layout ----------------
static constexpr size_t SZ_X1  = (size_t)64*1025*512*2;   // 67,174,400
static constexpr size_t SZ_X2  = (size_t)64*1025*256*2;   // 33,587,200
static constexpr size_t OFF_X1 = 0;
static constexpr size_t OFF_X2 = OFF_X1 + SZ_X1;
static constexpr size_t OFF_AUG = OFF_X2;                 // alias: aug dead after conv1
static constexpr size_t OFF_WT1 = OFF_X2 + SZ_X2;
static constexpr size_t OFF_WT2 = OFF_WT1 + (size_t)512*384*2;
static constexpr size_t OFF_WT3 = OFF_WT2 + (size_t)256*1536*2;
static constexpr size_t OFF_Q   = OFF_WT3 + (size_t)128*768*2;
static constexpr size_t OFF_ST  = OFF_Q + (size_t)64*32*4;
static constexpr size_t OFF_MAX = OFF_ST + (size_t)384*4;

extern "C" void kernel_launch(void* const* d_in, const int* in_sizes, int n_in,
                              void* d_out, int out_size, void* d_ws, size_t ws_size,
                              hipStream_t stream){
  const float* q_vecs = (const float*)d_in[0];
  const float* trees  = (const float*)d_in[1];
  const int*   idxes  = (const int*)  d_in[2];
  const float* Wq1 = (const float*)d_in[3];  const float* bq1 = (const float*)d_in[4];
  const float* Wq2 = (const float*)d_in[5];  const float* bq2 = (const float*)d_in[6];
  const float* Wq3 = (const float*)d_in[7];  const float* bq3 = (const float*)d_in[8];
  const float* Wq4 = (const float*)d_in[9];  const float* bq4 = (const float*)d_in[10];
  const float* Wc1 = (const float*)d_in[11]; const float* bc1 = (const float*)d_in[12];
  const float* Wc2 = (const float*)d_in[13]; const float* bc2 = (const float*)d_in[14];
  const float* Wc3 = (const float*)d_in[15]; const float* bc3 = (const float*)d_in[16];
  float* out = (float*)d_out;
  char* ws = (char*)d_ws;

  ushort* x1    = (ushort*)(ws + OFF_X1);
  ushort* x2    = (ushort*)(ws + OFF_X2);
  ushort* aug   = (ushort*)(ws + OFF_AUG);
  ushort* wt1   = (ushort*)(ws + OFF_WT1);
  ushort* wt2   = (ushort*)(ws + OFF_WT2);
  ushort* wt3   = (ushort*)(ws + OFF_WT3);
  float*  qbuf  = (float*) (ws + OFF_Q);
  float*  stats = (float*) (ws + OFF_ST);
  int*    maxb  = (int*)   (ws + OFF_MAX);

  init_kernel<<<128, 256, 0, stream>>>(x1, stats, maxb);
  qconv_kernel<<<64, 128, 0, stream>>>(q_vecs, Wq1,bq1, Wq2,bq2, Wq3,bq3, Wq4,bq4, qbuf);
  aug_kernel<<<dim3(1025, 64), 128, 0, stream>>>(trees, qbuf, aug);
  prepw_kernel<<<(512*384 + 255)/256, 256, 0, stream>>>(Wc1, wt1, 512, 128);
  prepw_kernel<<<(256*1536 + 255)/256, 256, 0, stream>>>(Wc2, wt2, 256, 512);
  prepw_kernel<<<(128*768 + 255)/256, 256, 0, stream>>>(Wc3, wt3, 128, 256);

  conv_kernel<128, 4, 128, false><<<2048, 256, 0, stream>>>(aug, wt1, bc1, idxes, x1, stats +   0, nullptr);
  zero2_kernel<<<64, 256, 0, stream>>>(x2);   // aug (aliased with x2) is dead now
  norm_kernel<<<dim3((65600 + 255)/256, 64), 256, 0, stream>>>(x1, stats +   0, 524800.f, 65600);
  conv_kernel<512, 2, 128, false><<<1024, 256, 0, stream>>>(x1,  wt2, bc2, idxes, x2, stats + 128, nullptr);
  norm_kernel<<<dim3((32800 + 255)/256, 64), 256, 0, stream>>>(x2, stats + 128, 262400.f, 32800);
  conv_kernel<256, 1, 64, true ><<<1024, 256, 0, stream>>>(x2,  wt3, bc3, idxes, nullptr, stats + 256, maxb);
  final_kernel<<<32, 256, 0, stream>>>(maxb, stats + 256, out);
}

// Round 12
// 266.812 us; speedup vs baseline: 1.5053x; 1.0187x over previous
//
#include <hip/hip_runtime.h>
#include <hip/hip_bf16.h>

typedef __attribute__((ext_vector_type(8))) short short8;
typedef __attribute__((ext_vector_type(4))) float f32x4;

#define EPSV 1e-5f

__device__ __forceinline__ float bf2f(ushort u){
  union { uint i; float f; } x; x.i = ((uint)u) << 16; return x.f;
}
__device__ __forceinline__ ushort f2bf(float f){
  union { float f; uint i; } x; x.f = f;
  uint r = (x.i + 0x7FFFu + ((x.i >> 16) & 1u)) >> 16;
  return (ushort)r;
}
// per-element: (v*rs + nmr) then leaky; applied to 8 bf16 packed in a uint4
__device__ __forceinline__ uint4 nrm8(uint4 v, float nmr, float rs){
  union { uint4 u; ushort s[8]; } x; x.u = v;
  #pragma unroll
  for (int k = 0; k < 8; ++k){
    float f = bf2f(x.s[k]);
    f = f * rs + nmr;
    f = fmaxf(f, 0.01f * f);      // leaky_relu(0.01)
    x.s[k] = f2bf(f);
  }
  return x.u;
}

// ---------------- init: zero stats, max accumulators, row 0 of x1 ----------------
__global__ void init_kernel(ushort* x1, float* stats, int* maxbuf){
  int i = blockIdx.x * 256 + threadIdx.x;   // 32768 threads
  if (i < 384)  stats[i] = 0.f;
  if (i < 8192) maxbuf[i] = 0;
  if (i < 32768){ int b = i >> 9, c = i & 511; x1[(size_t)b*1025*512 + c] = 0; }
}

// ---------------- zero node-0 rows of x2 (AFTER aug is dead: aug aliases x2) ----------------
__global__ void zero2_kernel(ushort* x2){
  int i = blockIdx.x * 256 + threadIdx.x;   // 16384 threads
  int b = i >> 8, c = i & 255;
  x2[(size_t)b*1025*256 + c] = 0;
}

// ---------------- q_conv: 4 stacked linears, no activations ----------------
__global__ void qconv_kernel(const float* __restrict__ qv,
    const float* __restrict__ W1, const float* __restrict__ b1,
    const float* __restrict__ W2, const float* __restrict__ b2,
    const float* __restrict__ W3, const float* __restrict__ b3,
    const float* __restrict__ W4, const float* __restrict__ b4,
    float* __restrict__ qout){
  __shared__ float v0[96], h1[64], h2[128], h3[64];
  int b = blockIdx.x, t = threadIdx.x;
  if (t < 95) v0[t] = qv[b*95 + t];
  __syncthreads();
  if (t < 64){ float s = b1[t]; for (int i=0;i<95;i++)  s += v0[i]*W1[i*64 + t];  h1[t]=s; }
  __syncthreads();
  if (t < 128){ float s = b2[t]; for (int i=0;i<64;i++)  s += h1[i]*W2[i*128 + t]; h2[t]=s; }
  __syncthreads();
  if (t < 64){ float s = b3[t]; for (int i=0;i<128;i++) s += h2[i]*W3[i*64 + t];  h3[t]=s; }
  __syncthreads();
  if (t < 32){ float s = b4[t]; for (int i=0;i<64;i++)  s += h3[i]*W4[i*32 + t];  qout[b*32 + t]=s; }
}

// ---------------- build augmented input (B,1025,128) bf16 ----------------
__global__ void aug_kernel(const float* __restrict__ trees, const float* __restrict__ q,
                           ushort* __restrict__ aug){
  int n = blockIdx.x;            // 0..1024
  int b = blockIdx.y;            // 0..63
  int c = threadIdx.x;           // 0..127
  float v = (c < 96) ? trees[((size_t)b*1025 + n)*96 + c] : q[b*32 + (c - 96)];
  aug[(((size_t)b*1025 + n) << 7) + c] = f2bf(v);
}

// ---------------- weight transpose: Wt[o][kp*C+c] = Wc[o][c][kp], bf16 ----------------
__global__ void prepw_kernel(const float* __restrict__ wc, ushort* __restrict__ wt,
                             int O, int C){
  int i = blockIdx.x * 256 + threadIdx.x;
  int total = O * 3 * C;
  if (i >= total) return;
  int o  = i / (3*C);
  int K  = i - o*3*C;
  int kp = K / C;
  int c  = K - kp*C;
  wt[i] = f2bf(wc[(o*C + c)*3 + kp]);
}

// ---------------- gathered conv as MFMA GEMM ----------------
// TM x 128 tile, BK=32, reg-staged 2-deep prefetch (R7 structure, best
// measured). LDS linear [buf][rows][32]; 16B-chunk XOR swizzle
// phys = log ^ ((row>>1)&3) on write AND read -> 0 conflicts (verified).
// NORM: previous layer's TreeLayerNorm+leaky fused into A staging (input is
// RAW prev-conv output incl. bias; per-batch mean/rs from its stats).
template<int CIN, int GY, int TM, bool DO_MAX, bool NORM>
__global__ __launch_bounds__(256) void conv_kernel(
    const ushort* __restrict__ xin, const ushort* __restrict__ wt,
    const float* __restrict__ bias, const int* __restrict__ idxes,
    ushort* __restrict__ xout, float* __restrict__ stats, int* __restrict__ maxbuf,
    const float* __restrict__ stats_prev, float cnt){
  constexpr int K3    = 3 * CIN;
  constexpr int NT    = K3 / 32;          // K-chunks of 32 (even)
  constexpr int LOG2  = (CIN == 128) ? 7 : (CIN == 256) ? 8 : 9;
  constexpr int MT    = 1024 / TM;
  constexpr int MF    = TM / 32;          // m-frags per wave
  constexpr int COUT  = GY * 128;
  constexpr int NWG   = MT * GY * 64;

  // XCD swizzle (verified FETCH drop): contiguous wu range per XCD.
  const int bid  = blockIdx.x;
  const int wu   = (bid & 7) * (NWG >> 3) + (bid >> 3);
  const int m0   = (wu % MT) * TM;
  const int rest = wu / MT;
  const int o0   = (rest % GY) * 128;
  const int b    = rest / GY;

  // fused-norm params (uniform per block)
  float nmr = 0.f, rsc = 0.f;
  if (NORM){
    float sum = stats_prev[b], sq = stats_prev[64 + b];
    float mean = sum / cnt;
    float var  = fmaxf((sq - sum*sum/cnt) / (cnt - 1.f), 0.f);
    rsc = 1.f / (sqrtf(var) + EPSV);
    nmr = -mean * rsc;
  }

  const int t = threadIdx.x;
  const int lane = t & 63, wid = t >> 6;
  const int WM = (wid & 1) * (TM/2), WO = (wid >> 1) * 64;
  const int fr = lane & 15, fg = lane >> 4;
  const int fc = (fg ^ ((fr >> 1) & 3)) * 8;   // swizzled read column (ushorts)

  __shared__ __align__(16) union {
    struct { ushort A[2][TM][32]; ushort B[2][128][32]; } s;
    ushort stage[TM][132];
  } sh;
  __shared__ int idx_s[3*TM];

  for (int i = t; i < 3*TM; i += 256) idx_s[i] = idxes[b*3072 + m0*3 + i];
  __syncthreads();

  // B staging: thread t -> row rB=t>>1, logical chunks 2h,2h+1 (h=t&1)
  const int rB = t >> 1, h = t & 1, sxB = (rB >> 1) & 3;
  const int pB0 = ((2*h)     ^ sxB) * 8;
  const int pB1 = ((2*h + 1) ^ sxB) * 8;
  const ushort* wrow = wt + (size_t)(o0 + rB) * K3 + h*16;

  // A staging geometry (TM=128: 2 chunks/thread; TM=64: 1 chunk/thread)
  const int rA  = (TM == 128) ? (t >> 1) : (t >> 2);
  const int qA  = (TM == 128) ? 0 : (t & 3);
  const int sxA = (rA >> 1) & 3;
  const int pA0 = (TM == 128) ? (((2*h) ^ sxA) * 8) : (((qA) ^ sxA) * 8);
  const int pA1 = ((2*h + 1) ^ sxA) * 8;                // TM=128 only
  const int aoff = (TM == 128) ? h*16 : qA*8;
  const int n0 = idx_s[rA*3 + 0], n1 = idx_s[rA*3 + 1], n2 = idx_s[rA*3 + 2];
  const ushort* xb   = xin + (size_t)b * 1025 * CIN;
  const ushort* pA0g = xb + (size_t)n0 * CIN + aoff;
  const ushort* pA1g = xb + (size_t)n1 * CIN + aoff;
  const ushort* pA2g = xb + (size_t)n2 * CIN + aoff;

  // two prefetch register sets — named scalars only (no scratch; R5 lesson)
  uint4 a00, a01, a10, a11, b00, b01, b10, b11;

  auto GLOAD0 = [&](int ch){
    const int k0 = ch * 32;
    const int kp = k0 >> LOG2;
    const int c0 = k0 - (kp << LOG2);
    const ushort* sa = ((kp == 0) ? pA0g : (kp == 1) ? pA1g : pA2g) + c0;
    a00 = *reinterpret_cast<const uint4*>(sa);
    if constexpr (TM == 128) a01 = *reinterpret_cast<const uint4*>(sa + 8);
    const ushort* sb = wrow + k0;
    b00 = *reinterpret_cast<const uint4*>(sb);
    b01 = *reinterpret_cast<const uint4*>(sb + 8);
  };
  auto GLOAD1 = [&](int ch){
    const int k0 = ch * 32;
    const int kp = k0 >> LOG2;
    const int c0 = k0 - (kp << LOG2);
    const ushort* sa = ((kp == 0) ? pA0g : (kp == 1) ? pA1g : pA2g) + c0;
    a10 = *reinterpret_cast<const uint4*>(sa);
    if constexpr (TM == 128) a11 = *reinterpret_cast<const uint4*>(sa + 8);
    const ushort* sb = wrow + k0;
    b10 = *reinterpret_cast<const uint4*>(sb);
    b11 = *reinterpret_cast<const uint4*>(sb + 8);
  };
  auto DSW0 = [&](int bf){
    uint4 w0 = NORM ? nrm8(a00, nmr, rsc) : a00;
    *reinterpret_cast<uint4*>(&sh.s.A[bf][rA][pA0]) = w0;
    if constexpr (TM == 128){
      uint4 w1 = NORM ? nrm8(a01, nmr, rsc) : a01;
      *reinterpret_cast<uint4*>(&sh.s.A[bf][rA][pA1]) = w1;
    }
    *reinterpret_cast<uint4*>(&sh.s.B[bf][rB][pB0]) = b00;
    *reinterpret_cast<uint4*>(&sh.s.B[bf][rB][pB1]) = b01;
  };
  auto DSW1 = [&](int bf){
    uint4 w0 = NORM ? nrm8(a10, nmr, rsc) : a10;
    *reinterpret_cast<uint4*>(&sh.s.A[bf][rA][pA0]) = w0;
    if constexpr (TM == 128){
      uint4 w1 = NORM ? nrm8(a11, nmr, rsc) : a11;
      *reinterpret_cast<uint4*>(&sh.s.A[bf][rA][pA1]) = w1;
    }
    *reinterpret_cast<uint4*>(&sh.s.B[bf][rB][pB0]) = b10;
    *reinterpret_cast<uint4*>(&sh.s.B[bf][rB][pB1]) = b11;
  };

  f32x4 acc[MF][4] = {};
  auto COMPUTE = [&](int cur){
    short8 af[MF], bf4[4];
    #pragma unroll
    for (int i = 0; i < MF; ++i)
      af[i] = *reinterpret_cast<const short8*>(&sh.s.A[cur][WM + i*16 + fr][fc]);
    #pragma unroll
    for (int i = 0; i < 4; ++i)
      bf4[i] = *reinterpret_cast<const short8*>(&sh.s.B[cur][WO + i*16 + fr][fc]);
    __builtin_amdgcn_s_setprio(1);
    #pragma unroll
    for (int mf = 0; mf < MF; ++mf)
      #pragma unroll
      for (int nf = 0; nf < 4; ++nf)
        acc[mf][nf] = __builtin_amdgcn_mfma_f32_16x16x32_bf16(af[mf], bf4[nf], acc[mf][nf], 0, 0, 0);
    __builtin_amdgcn_s_setprio(0);
  };

  // prologue: chunk0 -> LDS buf0, chunk1 -> set1
  GLOAD0(0);
  DSW0(0);
  GLOAD1(1);
  __syncthreads();

  for (int ch = 0; ch < NT; ch += 2){
    if (ch + 2 < NT) GLOAD0(ch + 2);     // issue 2 ahead
    COMPUTE(0);
    DSW1(1);                             // waits only set1's loads
    __syncthreads();
    if (ch + 3 < NT) GLOAD1(ch + 3);
    COMPUTE(1);
    if (ch + 2 < NT){
      DSW0(0);
      __syncthreads();
    }
  }

  // ---- epilogue: bias, stats, optional max, staged coalesced store ----
  float bsv[4];
  #pragma unroll
  for (int nf = 0; nf < 4; ++nf) bsv[nf] = bias[o0 + WO + nf*16 + fr];
  float lsum = 0.f, lsq = 0.f;
  float cmax[4] = { -1e30f, -1e30f, -1e30f, -1e30f };
  #pragma unroll
  for (int mf = 0; mf < MF; ++mf)
    #pragma unroll
    for (int nf = 0; nf < 4; ++nf)
      #pragma unroll
      for (int i = 0; i < 4; ++i){
        float v = acc[mf][nf][i] + bsv[nf];
        lsum += v; lsq += v*v;
        if (DO_MAX) cmax[nf] = fmaxf(cmax[nf], v);
        else acc[mf][nf][i] = v;
      }
  #pragma unroll
  for (int off = 1; off < 64; off <<= 1){
    lsum += __shfl_xor(lsum, off);
    lsq  += __shfl_xor(lsq,  off);
  }
  if (lane == 0){
    atomicAdd(&stats[b],      lsum);
    atomicAdd(&stats[64 + b], lsq);
  }
  if (DO_MAX){
    #pragma unroll
    for (int nf = 0; nf < 4; ++nf){
      float v = cmax[nf];
      v = fmaxf(v, __shfl_xor(v, 16));
      v = fmaxf(v, __shfl_xor(v, 32));
      if (lane < 16)
        atomicMax(&maxbuf[b*COUT + o0 + WO + nf*16 + fr], __float_as_int(v));
    }
  } else {
    __syncthreads();   // all waves done with K-buffers; reuse as staging
    #pragma unroll
    for (int mf = 0; mf < MF; ++mf)
      #pragma unroll
      for (int nf = 0; nf < 4; ++nf)
        #pragma unroll
        for (int i = 0; i < 4; ++i)
          sh.stage[WM + mf*16 + fg*4 + i][WO + nf*16 + fr] = f2bf(acc[mf][nf][i]);
    __syncthreads();
    #pragma unroll
    for (int it = 0; it < TM/8; ++it){
      int row = it*8 + (t >> 5);
      int col = (t & 31) * 4;
      uint2 v = *reinterpret_cast<const uint2*>(&sh.stage[row][col]);
      *reinterpret_cast<uint2*>(xout + ((size_t)(b*1025 + 1 + m0 + row))*COUT + o0 + col) = v;
    }
  }
}

// ---------------- final: normalize the per-channel max ----------------
__global__ void final_kernel(const int* __restrict__ maxbuf, const float* __restrict__ st,
                             float* __restrict__ out){
  int i = blockIdx.x * 256 + threadIdx.x;   // 8192
  int b = i >> 7;
  const float cnt = 131200.f;
  float sum = st[b], sq = st[64 + b];
  float mean = sum / cnt;
  float var  = fmaxf((sq - sum*sum/cnt) / (cnt - 1.f), 0.f);
  float rs   = 1.f / (sqrtf(var) + EPSV);
  out[i] = (__int_as_float(maxbuf[i]) - mean) * rs;
}

// ---------------- workspace layout ----------------
static constexpr size_t SZ_X1  = (size_t)64*1025*512*2;   // 67,174,400
static constexpr size_t SZ_X2  = (size_t)64*1025*256*2;   // 33,587,200
static constexpr size_t OFF_X1 = 0;
static constexpr size_t OFF_X2 = OFF_X1 + SZ_X1;
static constexpr size_t OFF_AUG = OFF_X2;                 // alias: aug dead after conv1
static constexpr size_t OFF_WT1 = OFF_X2 + SZ_X2;
static constexpr size_t OFF_WT2 = OFF_WT1 + (size_t)512*384*2;
static constexpr size_t OFF_WT3 = OFF_WT2 + (size_t)256*1536*2;
static constexpr size_t OFF_Q   = OFF_WT3 + (size_t)128*768*2;
static constexpr size_t OFF_ST  = OFF_Q + (size_t)64*32*4;
static constexpr size_t OFF_MAX = OFF_ST + (size_t)384*4;

extern "C" void kernel_launch(void* const* d_in, const int* in_sizes, int n_in,
                              void* d_out, int out_size, void* d_ws, size_t ws_size,
                              hipStream_t stream){
  const float* q_vecs = (const float*)d_in[0];
  const float* trees  = (const float*)d_in[1];
  const int*   idxes  = (const int*)  d_in[2];
  const float* Wq1 = (const float*)d_in[3];  const float* bq1 = (const float*)d_in[4];
  const float* Wq2 = (const float*)d_in[5];  const float* bq2 = (const float*)d_in[6];
  const float* Wq3 = (const float*)d_in[7];  const float* bq3 = (const float*)d_in[8];
  const float* Wq4 = (const float*)d_in[9];  const float* bq4 = (const float*)d_in[10];
  const float* Wc1 = (const float*)d_in[11]; const float* bc1 = (const float*)d_in[12];
  const float* Wc2 = (const float*)d_in[13]; const float* bc2 = (const float*)d_in[14];
  const float* Wc3 = (const float*)d_in[15]; const float* bc3 = (const float*)d_in[16];
  float* out = (float*)d_out;
  char* ws = (char*)d_ws;

  ushort* x1    = (ushort*)(ws + OFF_X1);
  ushort* x2    = (ushort*)(ws + OFF_X2);
  ushort* aug   = (ushort*)(ws + OFF_AUG);
  ushort* wt1   = (ushort*)(ws + OFF_WT1);
  ushort* wt2   = (ushort*)(ws + OFF_WT2);
  ushort* wt3   = (ushort*)(ws + OFF_WT3);
  float*  qbuf  = (float*) (ws + OFF_Q);
  float*  stats = (float*) (ws + OFF_ST);
  int*    maxb  = (int*)   (ws + OFF_MAX);

  init_kernel<<<128, 256, 0, stream>>>(x1, stats, maxb);
  qconv_kernel<<<64, 128, 0, stream>>>(q_vecs, Wq1,bq1, Wq2,bq2, Wq3,bq3, Wq4,bq4, qbuf);
  aug_kernel<<<dim3(1025, 64), 128, 0, stream>>>(trees, qbuf, aug);
  prepw_kernel<<<(512*384 + 255)/256, 256, 0, stream>>>(Wc1, wt1, 512, 128);
  prepw_kernel<<<(256*1536 + 255)/256, 256, 0, stream>>>(Wc2, wt2, 256, 512);
  prepw_kernel<<<(128*768 + 255)/256, 256, 0, stream>>>(Wc3, wt3, 128, 256);

  // conv1: aug -> x1 (raw+bias). conv2: raw x1 (+fused norm1) -> x2 (raw+bias).
  // conv3: raw x2 (+fused norm2) -> max accumulators.
  conv_kernel<128, 4, 128, false, false><<<2048, 256, 0, stream>>>(
      aug, wt1, bc1, idxes, x1, stats + 0, nullptr, nullptr, 1.f);
  zero2_kernel<<<64, 256, 0, stream>>>(x2);   // aug (aliased with x2) is dead now
  conv_kernel<512, 2, 128, false, true><<<1024, 256, 0, stream>>>(
      x1, wt2, bc2, idxes, x2, stats + 128, nullptr, stats + 0, 524800.f);
  conv_kernel<256, 1, 64, true, true><<<1024, 256, 0, stream>>>(
      x2, wt3, bc3, idxes, nullptr, stats + 256, maxb, stats + 128, 262400.f);
  final_kernel<<<32, 256, 0, stream>>>(maxb, stats + 256, out);
}

// Round 13
// 259.407 us; speedup vs baseline: 1.5483x; 1.0285x over previous
//
#include <hip/hip_runtime.h>
#include <hip/hip_bf16.h>

typedef __attribute__((ext_vector_type(8))) short short8;
typedef __attribute__((ext_vector_type(4))) float f32x4;

#define EPSV 1e-5f

__device__ __forceinline__ float bf2f(ushort u){
  union { uint i; float f; } x; x.i = ((uint)u) << 16; return x.f;
}
__device__ __forceinline__ ushort f2bf(float f){
  union { float f; uint i; } x; x.f = f;
  uint r = (x.i + 0x7FFFu + ((x.i >> 16) & 1u)) >> 16;
  return (ushort)r;
}

// raw barrier: LDS ops drained (lgkmcnt 0), global prefetches STAY IN FLIGHT
// (no vmcnt drain — the __syncthreads stall documented in the guide).
__device__ __forceinline__ void lds_barrier(){
  asm volatile("s_waitcnt lgkmcnt(0)" ::: "memory");
  __builtin_amdgcn_s_barrier();
}

// norm+leaky on 2 packed bf16 via v_cvt_pk_bf16_f32 (1 pack instr per pair)
__device__ __forceinline__ uint nrm2(uint u, float nmr, float rs){
  float lo = __uint_as_float(u << 16);
  float hi = __uint_as_float(u & 0xFFFF0000u);
  lo = fmaf(lo, rs, nmr);  hi = fmaf(hi, rs, nmr);
  lo = fmaxf(lo, 0.01f * lo);  hi = fmaxf(hi, 0.01f * hi);
  __hip_bfloat162 p = __float22bfloat162_rn(float2{lo, hi});
  return *reinterpret_cast<uint*>(&p);
}
__device__ __forceinline__ uint4 nrm8(uint4 v, float nmr, float rs){
  uint4 r;
  r.x = nrm2(v.x, nmr, rs);  r.y = nrm2(v.y, nmr, rs);
  r.z = nrm2(v.z, nmr, rs);  r.w = nrm2(v.w, nmr, rs);
  return r;
}

// ---------------- init: zero stats, max accumulators, row 0 of x1 ----------------
__global__ void init_kernel(ushort* x1, float* stats, int* maxbuf){
  int i = blockIdx.x * 256 + threadIdx.x;   // 32768 threads
  if (i < 384)  stats[i] = 0.f;
  if (i < 8192) maxbuf[i] = 0;
  if (i < 32768){ int b = i >> 9, c = i & 511; x1[(size_t)b*1025*512 + c] = 0; }
}

// ---------------- zero node-0 rows of x2 (AFTER aug is dead: aug aliases x2) ----------------
__global__ void zero2_kernel(ushort* x2){
  int i = blockIdx.x * 256 + threadIdx.x;   // 16384 threads
  int b = i >> 8, c = i & 255;
  x2[(size_t)b*1025*256 + c] = 0;
}

// ---------------- q_conv: 4 stacked linears, no activations ----------------
__global__ void qconv_kernel(const float* __restrict__ qv,
    const float* __restrict__ W1, const float* __restrict__ b1,
    const float* __restrict__ W2, const float* __restrict__ b2,
    const float* __restrict__ W3, const float* __restrict__ b3,
    const float* __restrict__ W4, const float* __restrict__ b4,
    float* __restrict__ qout){
  __shared__ float v0[96], h1[64], h2[128], h3[64];
  int b = blockIdx.x, t = threadIdx.x;
  if (t < 95) v0[t] = qv[b*95 + t];
  __syncthreads();
  if (t < 64){ float s = b1[t]; for (int i=0;i<95;i++)  s += v0[i]*W1[i*64 + t];  h1[t]=s; }
  __syncthreads();
  if (t < 128){ float s = b2[t]; for (int i=0;i<64;i++)  s += h1[i]*W2[i*128 + t]; h2[t]=s; }
  __syncthreads();
  if (t < 64){ float s = b3[t]; for (int i=0;i<128;i++) s += h2[i]*W3[i*64 + t];  h3[t]=s; }
  __syncthreads();
  if (t < 32){ float s = b4[t]; for (int i=0;i<64;i++)  s += h3[i]*W4[i*32 + t];  qout[b*32 + t]=s; }
}

// ---------------- build augmented input (B,1025,128) bf16 ----------------
__global__ void aug_kernel(const float* __restrict__ trees, const float* __restrict__ q,
                           ushort* __restrict__ aug){
  int n = blockIdx.x;            // 0..1024
  int b = blockIdx.y;            // 0..63
  int c = threadIdx.x;           // 0..127
  float v = (c < 96) ? trees[((size_t)b*1025 + n)*96 + c] : q[b*32 + (c - 96)];
  aug[(((size_t)b*1025 + n) << 7) + c] = f2bf(v);
}

// ---------------- weight transpose: Wt[o][kp*C+c] = Wc[o][c][kp], bf16 ----------------
__global__ void prepw_kernel(const float* __restrict__ wc, ushort* __restrict__ wt,
                             int O, int C){
  int i = blockIdx.x * 256 + threadIdx.x;
  int total = O * 3 * C;
  if (i >= total) return;
  int o  = i / (3*C);
  int K  = i - o*3*C;
  int kp = K / C;
  int c  = K - kp*C;
  wt[i] = f2bf(wc[(o*C + c)*3 + kp]);
}

// ---------------- gathered conv as MFMA GEMM ----------------
// TM x 128 tile, BK=32, reg-staged 2-deep prefetch. In-loop barriers are
// lgkm-only (prefetches survive; counted vmcnt at DSW). LDS 16B-chunk XOR
// swizzle phys = log ^ ((row>>1)&3) on write AND read -> 0 conflicts.
// NORM: prev layer's TreeLayerNorm+leaky fused into A staging (cvt_pk pack).
template<int CIN, int GY, int TM, bool DO_MAX, bool NORM>
__global__ __launch_bounds__(256) void conv_kernel(
    const ushort* __restrict__ xin, const ushort* __restrict__ wt,
    const float* __restrict__ bias, const int* __restrict__ idxes,
    ushort* __restrict__ xout, float* __restrict__ stats, int* __restrict__ maxbuf,
    const float* __restrict__ stats_prev, float cnt){
  constexpr int K3    = 3 * CIN;
  constexpr int NT    = K3 / 32;          // K-chunks of 32 (even)
  constexpr int LOG2  = (CIN == 128) ? 7 : (CIN == 256) ? 8 : 9;
  constexpr int MT    = 1024 / TM;
  constexpr int MF    = TM / 32;          // m-frags per wave
  constexpr int COUT  = GY * 128;
  constexpr int NWG   = MT * GY * 64;

  // XCD swizzle (verified FETCH drop): contiguous wu range per XCD.
  const int bid  = blockIdx.x;
  const int wu   = (bid & 7) * (NWG >> 3) + (bid >> 3);
  const int m0   = (wu % MT) * TM;
  const int rest = wu / MT;
  const int o0   = (rest % GY) * 128;
  const int b    = rest / GY;

  // fused-norm params (uniform per block)
  float nmr = 0.f, rsc = 0.f;
  if (NORM){
    float sum = stats_prev[b], sq = stats_prev[64 + b];
    float mean = sum / cnt;
    float var  = fmaxf((sq - sum*sum/cnt) / (cnt - 1.f), 0.f);
    rsc = 1.f / (sqrtf(var) + EPSV);
    nmr = -mean * rsc;
  }

  const int t = threadIdx.x;
  const int lane = t & 63, wid = t >> 6;
  const int WM = (wid & 1) * (TM/2), WO = (wid >> 1) * 64;
  const int fr = lane & 15, fg = lane >> 4;
  const int fc = (fg ^ ((fr >> 1) & 3)) * 8;   // swizzled read column (ushorts)

  __shared__ __align__(16) union {
    struct { ushort A[2][TM][32]; ushort B[2][128][32]; } s;
    ushort stage[TM][132];
  } sh;
  __shared__ int idx_s[3*TM];

  for (int i = t; i < 3*TM; i += 256) idx_s[i] = idxes[b*3072 + m0*3 + i];
  __syncthreads();

  // B staging: thread t -> row rB=t>>1, logical chunks 2h,2h+1 (h=t&1)
  const int rB = t >> 1, h = t & 1, sxB = (rB >> 1) & 3;
  const int pB0 = ((2*h)     ^ sxB) * 8;
  const int pB1 = ((2*h + 1) ^ sxB) * 8;
  const ushort* wrow = wt + (size_t)(o0 + rB) * K3 + h*16;

  // A staging geometry (TM=128: 2 chunks/thread; TM=64: 1 chunk/thread)
  const int rA  = (TM == 128) ? (t >> 1) : (t >> 2);
  const int qA  = (TM == 128) ? 0 : (t & 3);
  const int sxA = (rA >> 1) & 3;
  const int pA0 = (TM == 128) ? (((2*h) ^ sxA) * 8) : (((qA) ^ sxA) * 8);
  const int pA1 = ((2*h + 1) ^ sxA) * 8;                // TM=128 only
  const int aoff = (TM == 128) ? h*16 : qA*8;
  const int n0 = idx_s[rA*3 + 0], n1 = idx_s[rA*3 + 1], n2 = idx_s[rA*3 + 2];
  const ushort* xb   = xin + (size_t)b * 1025 * CIN;
  const ushort* pA0g = xb + (size_t)n0 * CIN + aoff;
  const ushort* pA1g = xb + (size_t)n1 * CIN + aoff;
  const ushort* pA2g = xb + (size_t)n2 * CIN + aoff;

  // two prefetch register sets — named scalars only (no scratch; R5 lesson)
  uint4 a00, a01, a10, a11, b00, b01, b10, b11;

  auto GLOAD0 = [&](int ch){
    const int k0 = ch * 32;
    const int kp = k0 >> LOG2;
    const int c0 = k0 - (kp << LOG2);
    const ushort* sa = ((kp == 0) ? pA0g : (kp == 1) ? pA1g : pA2g) + c0;
    a00 = *reinterpret_cast<const uint4*>(sa);
    if constexpr (TM == 128) a01 = *reinterpret_cast<const uint4*>(sa + 8);
    const ushort* sb = wrow + k0;
    b00 = *reinterpret_cast<const uint4*>(sb);
    b01 = *reinterpret_cast<const uint4*>(sb + 8);
  };
  auto GLOAD1 = [&](int ch){
    const int k0 = ch * 32;
    const int kp = k0 >> LOG2;
    const int c0 = k0 - (kp << LOG2);
    const ushort* sa = ((kp == 0) ? pA0g : (kp == 1) ? pA1g : pA2g) + c0;
    a10 = *reinterpret_cast<const uint4*>(sa);
    if constexpr (TM == 128) a11 = *reinterpret_cast<const uint4*>(sa + 8);
    const ushort* sb = wrow + k0;
    b10 = *reinterpret_cast<const uint4*>(sb);
    b11 = *reinterpret_cast<const uint4*>(sb + 8);
  };
  auto DSW0 = [&](int bf){
    uint4 w0 = NORM ? nrm8(a00, nmr, rsc) : a00;
    *reinterpret_cast<uint4*>(&sh.s.A[bf][rA][pA0]) = w0;
    if constexpr (TM == 128){
      uint4 w1 = NORM ? nrm8(a01, nmr, rsc) : a01;
      *reinterpret_cast<uint4*>(&sh.s.A[bf][rA][pA1]) = w1;
    }
    *reinterpret_cast<uint4*>(&sh.s.B[bf][rB][pB0]) = b00;
    *reinterpret_cast<uint4*>(&sh.s.B[bf][rB][pB1]) = b01;
  };
  auto DSW1 = [&](int bf){
    uint4 w0 = NORM ? nrm8(a10, nmr, rsc) : a10;
    *reinterpret_cast<uint4*>(&sh.s.A[bf][rA][pA0]) = w0;
    if constexpr (TM == 128){
      uint4 w1 = NORM ? nrm8(a11, nmr, rsc) : a11;
      *reinterpret_cast<uint4*>(&sh.s.A[bf][rA][pA1]) = w1;
    }
    *reinterpret_cast<uint4*>(&sh.s.B[bf][rB][pB0]) = b10;
    *reinterpret_cast<uint4*>(&sh.s.B[bf][rB][pB1]) = b11;
  };

  f32x4 acc[MF][4] = {};
  auto COMPUTE = [&](int cur){
    short8 af[MF], bf4[4];
    #pragma unroll
    for (int i = 0; i < MF; ++i)
      af[i] = *reinterpret_cast<const short8*>(&sh.s.A[cur][WM + i*16 + fr][fc]);
    #pragma unroll
    for (int i = 0; i < 4; ++i)
      bf4[i] = *reinterpret_cast<const short8*>(&sh.s.B[cur][WO + i*16 + fr][fc]);
    __builtin_amdgcn_s_setprio(1);
    #pragma unroll
    for (int mf = 0; mf < MF; ++mf)
      #pragma unroll
      for (int nf = 0; nf < 4; ++nf)
        acc[mf][nf] = __builtin_amdgcn_mfma_f32_16x16x32_bf16(af[mf], bf4[nf], acc[mf][nf], 0, 0, 0);
    __builtin_amdgcn_s_setprio(0);
  };

  // prologue: chunk0 -> LDS buf0, chunk1 -> set1
  GLOAD0(0);
  DSW0(0);
  GLOAD1(1);
  lds_barrier();

  for (int ch = 0; ch < NT; ch += 2){
    if (ch + 2 < NT) GLOAD0(ch + 2);     // issue 2 ahead; survives barriers now
    COMPUTE(0);
    DSW1(1);                             // counted vmcnt: waits only set1 loads
    lds_barrier();
    if (ch + 3 < NT) GLOAD1(ch + 3);
    COMPUTE(1);
    if (ch + 2 < NT){
      DSW0(0);
      lds_barrier();
    }
  }

  // ---- epilogue: bias, stats, optional max, staged coalesced store ----
  float bsv[4];
  #pragma unroll
  for (int nf = 0; nf < 4; ++nf) bsv[nf] = bias[o0 + WO + nf*16 + fr];
  float lsum = 0.f, lsq = 0.f;
  float cmax[4] = { -1e30f, -1e30f, -1e30f, -1e30f };
  #pragma unroll
  for (int mf = 0; mf < MF; ++mf)
    #pragma unroll
    for (int nf = 0; nf < 4; ++nf)
      #pragma unroll
      for (int i = 0; i < 4; ++i){
        float v = acc[mf][nf][i] + bsv[nf];
        lsum += v; lsq += v*v;
        if (DO_MAX) cmax[nf] = fmaxf(cmax[nf], v);
        else acc[mf][nf][i] = v;
      }
  #pragma unroll
  for (int off = 1; off < 64; off <<= 1){
    lsum += __shfl_xor(lsum, off);
    lsq  += __shfl_xor(lsq,  off);
  }
  if (lane == 0){
    atomicAdd(&stats[b],      lsum);
    atomicAdd(&stats[64 + b], lsq);
  }
  if (DO_MAX){
    #pragma unroll
    for (int nf = 0; nf < 4; ++nf){
      float v = cmax[nf];
      v = fmaxf(v, __shfl_xor(v, 16));
      v = fmaxf(v, __shfl_xor(v, 32));
      if (lane < 16)
        atomicMax(&maxbuf[b*COUT + o0 + WO + nf*16 + fr], __float_as_int(v));
    }
  } else {
    __syncthreads();   // all waves done with K-buffers; reuse as staging
    #pragma unroll
    for (int mf = 0; mf < MF; ++mf)
      #pragma unroll
      for (int nf = 0; nf < 4; ++nf)
        #pragma unroll
        for (int i = 0; i < 4; ++i)
          sh.stage[WM + mf*16 + fg*4 + i][WO + nf*16 + fr] = f2bf(acc[mf][nf][i]);
    __syncthreads();
    #pragma unroll
    for (int it = 0; it < TM/8; ++it){
      int row = it*8 + (t >> 5);
      int col = (t & 31) * 4;
      uint2 v = *reinterpret_cast<const uint2*>(&sh.stage[row][col]);
      *reinterpret_cast<uint2*>(xout + ((size_t)(b*1025 + 1 + m0 + row))*COUT + o0 + col) = v;
    }
  }
}

// ---------------- final: normalize the per-channel max ----------------
__global__ void final_kernel(const int* __restrict__ maxbuf, const float* __restrict__ st,
                             float* __restrict__ out){
  int i = blockIdx.x * 256 + threadIdx.x;   // 8192
  int b = i >> 7;
  const float cnt = 131200.f;
  float sum = st[b], sq = st[64 + b];
  float mean = sum / cnt;
  float var  = fmaxf((sq - sum*sum/cnt) / (cnt - 1.f), 0.f);
  float rs   = 1.f / (sqrtf(var) + EPSV);
  out[i] = (__int_as_float(maxbuf[i]) - mean) * rs;
}

// ---------------- workspace layout ----------------
static constexpr size_t SZ_X1  = (size_t)64*1025*512*2;   // 67,174,400
static constexpr size_t SZ_X2  = (size_t)64*1025*256*2;   // 33,587,200
static constexpr size_t OFF_X1 = 0;
static constexpr size_t OFF_X2 = OFF_X1 + SZ_X1;
static constexpr size_t OFF_AUG = OFF_X2;                 // alias: aug dead after conv1
static constexpr size_t OFF_WT1 = OFF_X2 + SZ_X2;
static constexpr size_t OFF_WT2 = OFF_WT1 + (size_t)512*384*2;
static constexpr size_t OFF_WT3 = OFF_WT2 + (size_t)256*1536*2;
static constexpr size_t OFF_Q   = OFF_WT3 + (size_t)128*768*2;
static constexpr size_t OFF_ST  = OFF_Q + (size_t)64*32*4;
static constexpr size_t OFF_MAX = OFF_ST + (size_t)384*4;

extern "C" void kernel_launch(void* const* d_in, const int* in_sizes, int n_in,
                              void* d_out, int out_size, void* d_ws, size_t ws_size,
                              hipStream_t stream){
  const float* q_vecs = (const float*)d_in[0];
  const float* trees  = (const float*)d_in[1];
  const int*   idxes  = (const int*)  d_in[2];
  const float* Wq1 = (const float*)d_in[3];  const float* bq1 = (const float*)d_in[4];
  const float* Wq2 = (const float*)d_in[5];  const float* bq2 = (const float*)d_in[6];
  const float* Wq3 = (const float*)d_in[7];  const float* bq3 = (const float*)d_in[8];
  const float* Wq4 = (const float*)d_in[9];  const float* bq4 = (const float*)d_in[10];
  const float* Wc1 = (const float*)d_in[11]; const float* bc1 = (const float*)d_in[12];
  const float* Wc2 = (const float*)d_in[13]; const float* bc2 = (const float*)d_in[14];
  const float* Wc3 = (const float*)d_in[15]; const float* bc3 = (const float*)d_in[16];
  float* out = (float*)d_out;
  char* ws = (char*)d_ws;

  ushort* x1    = (ushort*)(ws + OFF_X1);
  ushort* x2    = (ushort*)(ws + OFF_X2);
  ushort* aug   = (ushort*)(ws + OFF_AUG);
  ushort* wt1   = (ushort*)(ws + OFF_WT1);
  ushort* wt2   = (ushort*)(ws + OFF_WT2);
  ushort* wt3   = (ushort*)(ws + OFF_WT3);
  float*  qbuf  = (float*) (ws + OFF_Q);
  float*  stats = (float*) (ws + OFF_ST);
  int*    maxb  = (int*)   (ws + OFF_MAX);

  init_kernel<<<128, 256, 0, stream>>>(x1, stats, maxb);
  qconv_kernel<<<64, 128, 0, stream>>>(q_vecs, Wq1,bq1, Wq2,bq2, Wq3,bq3, Wq4,bq4, qbuf);
  aug_kernel<<<dim3(1025, 64), 128, 0, stream>>>(trees, qbuf, aug);
  prepw_kernel<<<(512*384 + 255)/256, 256, 0, stream>>>(Wc1, wt1, 512, 128);
  prepw_kernel<<<(256*1536 + 255)/256, 256, 0, stream>>>(Wc2, wt2, 256, 512);
  prepw_kernel<<<(128*768 + 255)/256, 256, 0, stream>>>(Wc3, wt3, 128, 256);

  // conv1: aug -> x1 (raw+bias). conv2: raw x1 (+fused norm1) -> x2 (raw+bias).
  // conv3: raw x2 (+fused norm2) -> max accumulators.
  conv_kernel<128, 4, 128, false, false><<<2048, 256, 0, stream>>>(
      aug, wt1, bc1, idxes, x1, stats + 0, nullptr, nullptr, 1.f);
  zero2_kernel<<<64, 256, 0, stream>>>(x2);   // aug (aliased with x2) is dead now
  conv_kernel<512, 2, 128, false, true><<<1024, 256, 0, stream>>>(
      x1, wt2, bc2, idxes, x2, stats + 128, nullptr, stats + 0, 524800.f);
  conv_kernel<256, 1, 64, true, true><<<1024, 256, 0, stream>>>(
      x2, wt3, bc3, idxes, nullptr, stats + 256, maxb, stats + 128, 262400.f);
  final_kernel<<<32, 256, 0, stream>>>(maxb, stats + 256, out);
}